// Round 4
// baseline (527.212 us; speedup 1.0000x reference)
//
#include <hip/hip_runtime.h>
#include <hip/hip_bf16.h>

typedef __attribute__((ext_vector_type(8))) short s16x8;
typedef __attribute__((ext_vector_type(4))) float f32x4;
typedef unsigned short u16;

#define NB 16
#define NK 256
#define APP 768
#define DKK 96
#define NR 8
#define QSCALE 0.10206207261596575f   // 1/sqrt(96), folded into Q at projection

__device__ __forceinline__ u16 f2bf(float f) {
  union { float f; unsigned int u; } v; v.f = f;
  unsigned int x = v.u;
  x += 0x7fffu + ((x >> 16) & 1u);
  return (u16)(x >> 16);
}
__device__ __forceinline__ float bf2f(u16 h) {
  union { unsigned int u; float f; } v; v.u = ((unsigned int)h) << 16;
  return v.f;
}
__device__ __forceinline__ void gload_lds16(const void* g, void* l) {
  __builtin_amdgcn_global_load_lds(
      (const __attribute__((address_space(1))) unsigned int*)g,
      (__attribute__((address_space(3))) unsigned int*)l, 16, 0, 0);
}

// ---------------------------------------------------------------------------
// MEASUREMENT ROUND: code byte-identical to round 3. Only the launch sequence
// changes: fused_kernel x3, attn_kernel x2 (all idempotent/deterministic).
// dur4 = conv + 3*fused + 2*attn; with R3 (conv+fused+attn=196) and conv~5:
//   fused = dur4 - 387,  attn = 191 - fused.
// ---------------------------------------------------------------------------

__global__ __launch_bounds__(256) void conv_kernel(
    const float* __restrict__ fa,
    const float* __restrict__ WKw, const float* __restrict__ WQw,
    const float* __restrict__ WVw,
    u16* __restrict__ fab, u16* __restrict__ Wb)
{
  const int idx = blockIdx.x * 256 + threadIdx.x;
  const int faCh = NB * NK * APP / 8;      // 393216
  const int wCh  = NR * DKK * APP / 8;     // 73728 per weight array
  const float* src; u16* dst;
  if (idx < faCh) {
    src = fa + (size_t)idx * 8;
    dst = fab + (size_t)idx * 8;
  } else {
    int o = idx - faCh;
    int a = o / wCh;
    int oo = o - a * wCh;
    const float* wsrc = a == 0 ? WKw : (a == 1 ? WQw : WVw);
    src = wsrc + (size_t)oo * 8;
    dst = Wb + (size_t)a * (NR * DKK * APP) + (size_t)oo * 8;
  }
  float4 v0 = *(const float4*)src;
  float4 v1 = *(const float4*)(src + 4);
  s16x8 ov = {(short)f2bf(v0.x),(short)f2bf(v0.y),(short)f2bf(v0.z),(short)f2bf(v0.w),
              (short)f2bf(v1.x),(short)f2bf(v1.y),(short)f2bf(v1.z),(short)f2bf(v1.w)};
  *(s16x8*)dst = ov;
}

#define PROJ_BLKS 576
#define WG_BLKS 1024

__global__ __launch_bounds__(256) void fused_kernel(
    const u16* __restrict__ fab, const u16* __restrict__ Wb,
    const float* __restrict__ WKb, const float* __restrict__ WQb,
    const float* __restrict__ WVb,
    u16* __restrict__ wk, u16* __restrict__ wq, u16* __restrict__ wvT,
    const float* __restrict__ pos,
    const float* __restrict__ WGw, const float* __restrict__ WGb,
    u16* __restrict__ lb2)
{
  __shared__ u16 As[128 * 64];
  __shared__ u16 Bs[128 * 64];
  const int t = threadIdx.x;
  const int bid = blockIdx.x;
  const int grp = bid / 25, rem = bid % 25;

  if (rem < 9) {
    // ----------------------- proj path -----------------------
    const int pb = grp * 9 + rem;          // 0..575
    const int lane = t & 63, w = t >> 6;
    const int c = lane & 15, g = lane >> 4;
    const int wr = w >> 1, wc = w & 1;
    const int m0 = (pb & 31) * 128;
    const int ct = pb >> 5;                // 0..17
    const int c0 = ct * 128;

    f32x4 acc[4][4] = {};

    for (int k0 = 0; k0 < APP; k0 += 64) {
      __syncthreads();
      #pragma unroll
      for (int i = 0; i < 4; ++i) {
        int n = t + i * 256;               // chunk id, 0..1023
        int row = n >> 3, cg = n & 7;
        int scg = cg ^ (row & 7);          // pre-swizzled global col-group
        gload_lds16(fab + (size_t)(m0 + row) * APP + k0 + scg * 8, As + n * 8);
        gload_lds16(Wb  + (size_t)(c0 + row) * APP + k0 + scg * 8, Bs + n * 8);
      }
      __syncthreads();
      #pragma unroll
      for (int kc = 0; kc < 2; ++kc) {
        s16x8 af[4], bfr[4];
        #pragma unroll
        for (int i = 0; i < 4; ++i) {
          int arow = wr * 64 + i * 16 + c;
          af[i]  = *(const s16x8*)(As + (((arow << 3) | ((kc * 4 + g) ^ (arow & 7))) << 3));
          int brow = wc * 64 + i * 16 + c;
          bfr[i] = *(const s16x8*)(Bs + (((brow << 3) | ((kc * 4 + g) ^ (brow & 7))) << 3));
        }
        #pragma unroll
        for (int mi = 0; mi < 4; ++mi)
          #pragma unroll
          for (int ni = 0; ni < 4; ++ni)
            acc[mi][ni] = __builtin_amdgcn_mfma_f32_16x16x32_bf16(af[mi], bfr[ni], acc[mi][ni], 0, 0, 0);
      }
    }

    const int arr = ct / 6;                // 0=K 1=Q 2=V
    const int cw0 = c0 - arr * APP;
    const float* bp = arr == 0 ? WKb : (arr == 1 ? WQb : WVb);

    #pragma unroll
    for (int mi = 0; mi < 4; ++mi)
      #pragma unroll
      for (int ni = 0; ni < 4; ++ni) {
        int clw = cw0 + wc * 64 + ni * 16 + c;
        float bias = bp[clw];
        int rr = clw / DKK, kk = clw - rr * DKK;
        int mb = m0 + wr * 64 + mi * 16 + g * 4;     // 4 consecutive m
        int bi = mb >> 8, tt = mb & 255;
        if (arr == 2) {
          ushort4 pk;
          pk.x = f2bf(acc[mi][ni][0] + bias);
          pk.y = f2bf(acc[mi][ni][1] + bias);
          pk.z = f2bf(acc[mi][ni][2] + bias);
          pk.w = f2bf(acc[mi][ni][3] + bias);
          *(ushort4*)&wvT[(((size_t)rr * NB + bi) * DKK + kk) * NK + tt] = pk;
        } else {
          u16* op = arr == 0 ? wk : wq;
          #pragma unroll
          for (int e = 0; e < 4; ++e) {
            float val = acc[mi][ni][e] + bias;
            if (arr == 1) val *= QSCALE;
            op[(((size_t)rr * NB + bi) * NK + tt + e) * DKK + kk] = f2bf(val);
          }
        }
      }
  } else {
    // ----------------------- wg path -----------------------
    const int wb = grp * 16 + (rem - 9);   // 0..1023
    const int n0 = (wb & 7) * 32;
    const int m0 = ((wb >> 3) & 7) * 32;
    const int b = wb >> 6;
    const int slot = t >> 3, l8 = t & 7;

    float wreg[8][12];
    #pragma unroll
    for (int rr = 0; rr < 8; ++rr)
      #pragma unroll
      for (int u = 0; u < 12; ++u)
        wreg[rr][u] = WGw[rr * 96 + l8 * 12 + u];
    const float wb_b = WGb[l8];

    for (int i = 0; i < 32; ++i) {
      const float* p = pos + (((size_t)(b * NK + m0 + i) * NK) + n0 + slot) * 96 + l8 * 12;
      f32x4 q0 = __builtin_nontemporal_load((const f32x4*)p);
      f32x4 q1 = __builtin_nontemporal_load((const f32x4*)(p + 4));
      f32x4 q2 = __builtin_nontemporal_load((const f32x4*)(p + 8));
      float pv[12] = {q0[0],q0[1],q0[2],q0[3], q1[0],q1[1],q1[2],q1[3],
                      q2[0],q2[1],q2[2],q2[3]};
      float acc[8] = {0.f,0.f,0.f,0.f,0.f,0.f,0.f,0.f};
      #pragma unroll
      for (int u = 0; u < 12; ++u) {
        float x = pv[u];
        #pragma unroll
        for (int rr = 0; rr < 8; ++rr) acc[rr] += x * wreg[rr][u];
      }
      #pragma unroll
      for (int rr = 0; rr < 8; ++rr) {
        acc[rr] += __shfl_xor(acc[rr], 1);
        acc[rr] += __shfl_xor(acc[rr], 2);
        acc[rr] += __shfl_xor(acc[rr], 4);
      }
      float v = l8 < 4 ? (l8 < 2 ? (l8 == 0 ? acc[0] : acc[1])
                                 : (l8 == 2 ? acc[2] : acc[3]))
                       : (l8 < 6 ? (l8 == 4 ? acc[4] : acc[5])
                                 : (l8 == 6 ? acc[6] : acc[7]));
      v = __logf(fmaxf(v + wb_b, 1e-6f));
      lb2[(((size_t)l8 * NB + b) * NK + m0 + i) * NK + n0 + slot] = f2bf(v);
    }
  }
}

__global__ __launch_bounds__(256) void attn_kernel(
    const u16* __restrict__ wk, const u16* __restrict__ wq,
    const u16* __restrict__ wvT, const u16* __restrict__ lb2,
    const float* __restrict__ fa, float* __restrict__ out)
{
  __shared__ u16 Ps[4][16][40];   // per-wave P chunk [16 n][32 m]
  const int t = threadIdx.x;
  const int w = t >> 6, lane = t & 63;
  const int c = lane & 15, g = lane >> 4;
  const int b = blockIdx.y, r = blockIdx.z;
  const int nb = blockIdx.x * 64 + w * 16;

  const size_t hb = (size_t)r * NB + b;
  const u16* Qr = wq + (hb * NK + nb + c) * DKK + g * 8;
  const u16* Kr = wk + (hb * NK + c) * DKK + g * 8;
  const u16* Vr = wvT + (hb * DKK + c) * NK + g * 8;
  const u16* Br = lb2 + hb * NK * NK + (size_t)c * NK + nb + g * 4;

  s16x8 qf[3];
  #pragma unroll
  for (int kc = 0; kc < 3; ++kc) qf[kc] = *(const s16x8*)(Qr + kc * 32);

  ushort4 bbr[16];
  #pragma unroll
  for (int mt = 0; mt < 16; ++mt)
    bbr[mt] = *(const ushort4*)(Br + (size_t)mt * 16 * NK);

  f32x4 S[16];
  #pragma unroll
  for (int mt = 0; mt < 16; ++mt) {
    f32x4 sa = {bf2f(bbr[mt].x), bf2f(bbr[mt].y), bf2f(bbr[mt].z), bf2f(bbr[mt].w)};
    #pragma unroll
    for (int kc = 0; kc < 3; ++kc) {
      s16x8 kf = *(const s16x8*)(Kr + (size_t)mt * 16 * DKK + kc * 32);
      sa = __builtin_amdgcn_mfma_f32_16x16x32_bf16(qf[kc], kf, sa, 0, 0, 0);
    }
    S[mt] = sa;
  }

  float rinv[4];
  #pragma unroll
  for (int e = 0; e < 4; ++e) {
    float mx = S[0][e];
    #pragma unroll
    for (int mt = 1; mt < 16; ++mt) mx = fmaxf(mx, S[mt][e]);
    mx = fmaxf(mx, __shfl_xor(mx, 1));
    mx = fmaxf(mx, __shfl_xor(mx, 2));
    mx = fmaxf(mx, __shfl_xor(mx, 4));
    mx = fmaxf(mx, __shfl_xor(mx, 8));
    float sm = 0.f;
    #pragma unroll
    for (int mt = 0; mt < 16; ++mt) {
      float p = __expf(S[mt][e] - mx);
      S[mt][e] = p;
      sm += p;
    }
    sm += __shfl_xor(sm, 1);
    sm += __shfl_xor(sm, 2);
    sm += __shfl_xor(sm, 4);
    sm += __shfl_xor(sm, 8);
    rinv[e] = 1.f / sm;
  }

  f32x4 o[6];
  #pragma unroll
  for (int ki = 0; ki < 6; ++ki) o[ki] = (f32x4){0.f, 0.f, 0.f, 0.f};

  #pragma unroll
  for (int mc = 0; mc < 8; ++mc) {
    #pragma unroll
    for (int e = 0; e < 4; ++e) {
      Ps[w][g * 4 + e][c]      = f2bf(S[2 * mc][e]);
      Ps[w][g * 4 + e][16 + c] = f2bf(S[2 * mc + 1][e]);
    }
    s16x8 pa = *(const s16x8*)&Ps[w][c][g * 8];
    #pragma unroll
    for (int ki = 0; ki < 6; ++ki) {
      s16x8 vf = *(const s16x8*)(Vr + (size_t)(ki * 16) * NK + mc * 32);
      o[ki] = __builtin_amdgcn_mfma_f32_16x16x32_bf16(pa, vf, o[ki], 0, 0, 0);
    }
  }

  #pragma unroll
  for (int ki = 0; ki < 6; ++ki)
    #pragma unroll
    for (int e = 0; e < 4; ++e) {
      int n = nb + g * 4 + e;
      size_t adr = ((size_t)b * NK + n) * (NR * DKK) + r * DKK + ki * 16 + c;
      out[adr] = o[ki][e] * rinv[e] + fa[adr];
    }
}

extern "C" void kernel_launch(void* const* d_in, const int* in_sizes, int n_in,
                              void* d_out, int out_size, void* d_ws, size_t ws_size,
                              hipStream_t stream) {
  (void)in_sizes; (void)n_in; (void)out_size; (void)ws_size;
  const float* fa  = (const float*)d_in[0];
  const float* pos = (const float*)d_in[1];
  const float* WGw = (const float*)d_in[2];
  const float* WGb = (const float*)d_in[3];
  const float* WKw = (const float*)d_in[4];
  const float* WKb = (const float*)d_in[5];
  const float* WQw = (const float*)d_in[6];
  const float* WQb = (const float*)d_in[7];
  const float* WVw = (const float*)d_in[8];
  const float* WVb = (const float*)d_in[9];
  float* outp = (float*)d_out;

  const size_t faN = (size_t)NB * NK * APP;       // 3,145,728
  const size_t wN  = (size_t)3 * NR * DKK * APP;  // 1,769,472
  const size_t kqv = (size_t)NR * NB * NK * DKK;  // 3,145,728
  u16* fab = (u16*)d_ws;
  u16* Wb  = fab + faN;
  u16* wk  = Wb + wN;
  u16* wq  = wk + kqv;
  u16* wvT = wq + kqv;
  u16* lb2 = wvT + kqv;

  hipLaunchKernelGGL(conv_kernel, dim3(2400), dim3(256), 0, stream,
                     fa, WKw, WQw, WVw, fab, Wb);
  // MEASUREMENT: fused x3 (idempotent), attn x2 (idempotent).
  // dur = conv + 3*fused + 2*attn ; R3 gave conv + fused + attn = 196.
  hipLaunchKernelGGL(fused_kernel, dim3(PROJ_BLKS + WG_BLKS), dim3(256), 0, stream,
                     fab, Wb, WKb, WQb, WVb, wk, wq, wvT, pos, WGw, WGb, lb2);
  hipLaunchKernelGGL(fused_kernel, dim3(PROJ_BLKS + WG_BLKS), dim3(256), 0, stream,
                     fab, Wb, WKb, WQb, WVb, wk, wq, wvT, pos, WGw, WGb, lb2);
  hipLaunchKernelGGL(fused_kernel, dim3(PROJ_BLKS + WG_BLKS), dim3(256), 0, stream,
                     fab, Wb, WKb, WQb, WVb, wk, wq, wvT, pos, WGw, WGb, lb2);
  hipLaunchKernelGGL(attn_kernel, dim3(4, NB, NR), dim3(256), 0, stream,
                     wk, wq, wvT, lb2, fa, outp);
  hipLaunchKernelGGL(attn_kernel, dim3(4, NB, NR), dim3(256), 0, stream,
                     wk, wq, wvT, lb2, fa, outp);
}

// Round 6
// 146.536 us; speedup vs baseline: 3.5978x; 3.5978x over previous
//
#include <hip/hip_runtime.h>
#include <hip/hip_bf16.h>

typedef __attribute__((ext_vector_type(8))) short s16x8;
typedef __attribute__((ext_vector_type(4))) float f32x4;
typedef unsigned short u16;
typedef unsigned int u32;

#define NB 16
#define NK 256
#define APP 768
#define DKK 96
#define NR 8
#define QSCALE 0.10206207261596575f   // 1/sqrt(96), folded into Q at projection

__device__ __forceinline__ u16 f2bf(float f) {
  union { float f; unsigned int u; } v; v.f = f;
  unsigned int x = v.u;
  x += 0x7fffu + ((x >> 16) & 1u);
  return (u16)(x >> 16);
}
__device__ __forceinline__ float bf2f(u16 h) {
  union { unsigned int u; float f; } v; v.u = ((unsigned int)h) << 16;
  return v.f;
}
__device__ __forceinline__ u32 cvtpk(float lo, float hi) {
  u32 r;
  asm("v_cvt_pk_bf16_f32 %0, %1, %2" : "=v"(r) : "v"(lo), "v"(hi));
  return r;
}
__device__ __forceinline__ float bflo(u32 pk) {   // float of low bf16
  union { u32 u; float f; } v; v.u = pk << 16; return v.f;
}
__device__ __forceinline__ float bfhi(u32 pk) {   // float of high bf16
  union { u32 u; float f; } v; v.u = pk & 0xffff0000u; return v.f;
}
__device__ __forceinline__ void gload_lds16(const void* g, void* l) {
  __builtin_amdgcn_global_load_lds(
      (const __attribute__((address_space(1))) unsigned int*)g,
      (__attribute__((address_space(3))) unsigned int*)l, 16, 0, 0);
}

// ---------------------------------------------------------------------------
// Kernel 0: convert f_a and the 3 projection weights to bf16.
// ---------------------------------------------------------------------------
__global__ __launch_bounds__(256) void conv_kernel(
    const float* __restrict__ fa,
    const float* __restrict__ WKw, const float* __restrict__ WQw,
    const float* __restrict__ WVw,
    u16* __restrict__ fab, u16* __restrict__ Wb)
{
  const int idx = blockIdx.x * 256 + threadIdx.x;
  const int faCh = NB * NK * APP / 8;      // 393216
  const int wCh  = NR * DKK * APP / 8;     // 73728 per weight array
  const float* src; u16* dst;
  if (idx < faCh) {
    src = fa + (size_t)idx * 8;
    dst = fab + (size_t)idx * 8;
  } else {
    int o = idx - faCh;
    int a = o / wCh;
    int oo = o - a * wCh;
    const float* wsrc = a == 0 ? WKw : (a == 1 ? WQw : WVw);
    src = wsrc + (size_t)oo * 8;
    dst = Wb + (size_t)a * (NR * DKK * APP) + (size_t)oo * 8;
  }
  float4 v0 = *(const float4*)src;
  float4 v1 = *(const float4*)(src + 4);
  s16x8 ov = {(short)f2bf(v0.x),(short)f2bf(v0.y),(short)f2bf(v0.z),(short)f2bf(v0.w),
              (short)f2bf(v1.x),(short)f2bf(v1.y),(short)f2bf(v1.z),(short)f2bf(v1.w)};
  *(s16x8*)dst = ov;
}

// ---------------------------------------------------------------------------
// Kernel 1: projections (bf16 GEMM, m97 structure, 128x128 tile, BK=64).
// Outputs in FRAGMENT-MAJOR layouts so attention loads are dense 1-KB instrs:
//   wkF/wqF: [r][b][kg=12][m=256][8]   (Q pre-scaled by 1/sqrt(96))
//   wvF    : [r][b][mg=32][kout=96][8] (V "transposed" per 8-m groups)
// ---------------------------------------------------------------------------
__global__ __launch_bounds__(256) void proj_kernel(
    const u16* __restrict__ fab, const u16* __restrict__ Wb,
    const float* __restrict__ WKb, const float* __restrict__ WQb,
    const float* __restrict__ WVb,
    u16* __restrict__ wkF, u16* __restrict__ wqF, u16* __restrict__ wvF)
{
  __shared__ u16 As[128 * 64];   // linear (gld_lds dest), swizzled content
  __shared__ u16 Bs[128 * 64];
  const int t = threadIdx.x;
  const int lane = t & 63, w = t >> 6;
  const int c = lane & 15, g = lane >> 4;
  const int wr = w >> 1, wc = w & 1;
  const int m0 = blockIdx.x * 128;
  const int ct = blockIdx.y;             // 0..17
  const int c0 = ct * 128;

  f32x4 acc[4][4] = {};

  for (int k0 = 0; k0 < APP; k0 += 64) {
    __syncthreads();
    #pragma unroll
    for (int i = 0; i < 4; ++i) {
      int n = t + i * 256;               // chunk id, 0..1023
      int row = n >> 3, cg = n & 7;
      int scg = cg ^ (row & 7);          // pre-swizzled global col-group
      gload_lds16(fab + (size_t)(m0 + row) * APP + k0 + scg * 8, As + n * 8);
      gload_lds16(Wb  + (size_t)(c0 + row) * APP + k0 + scg * 8, Bs + n * 8);
    }
    __syncthreads();
    #pragma unroll
    for (int kc = 0; kc < 2; ++kc) {
      s16x8 af[4], bfr[4];
      #pragma unroll
      for (int i = 0; i < 4; ++i) {
        int arow = wr * 64 + i * 16 + c;
        af[i]  = *(const s16x8*)(As + (((arow << 3) | ((kc * 4 + g) ^ (arow & 7))) << 3));
        int brow = wc * 64 + i * 16 + c;
        bfr[i] = *(const s16x8*)(Bs + (((brow << 3) | ((kc * 4 + g) ^ (brow & 7))) << 3));
      }
      #pragma unroll
      for (int mi = 0; mi < 4; ++mi)
        #pragma unroll
        for (int ni = 0; ni < 4; ++ni)
          acc[mi][ni] = __builtin_amdgcn_mfma_f32_16x16x32_bf16(af[mi], bfr[ni], acc[mi][ni], 0, 0, 0);
    }
  }

  const int arr = ct / 6;                // 0=K 1=Q 2=V (tiles never straddle)
  const int cw0 = c0 - arr * APP;
  const float* bp = arr == 0 ? WKb : (arr == 1 ? WQb : WVb);

  #pragma unroll
  for (int mi = 0; mi < 4; ++mi)
    #pragma unroll
    for (int ni = 0; ni < 4; ++ni) {
      int clw = cw0 + wc * 64 + ni * 16 + c;    // 0..767
      float bias = bp[clw];
      int rr = clw / DKK, kk = clw - rr * DKK;  // r, k-within-head
      int mb = m0 + wr * 64 + mi * 16 + g * 4;  // 4 consecutive m
      int bi = mb >> 8, tt = mb & 255;
      size_t hb = (size_t)rr * NB + bi;
      if (arr == 2) {
        ushort4 pk4;
        pk4.x = f2bf(acc[mi][ni][0] + bias);
        pk4.y = f2bf(acc[mi][ni][1] + bias);
        pk4.z = f2bf(acc[mi][ni][2] + bias);
        pk4.w = f2bf(acc[mi][ni][3] + bias);
        *(ushort4*)&wvF[((hb * 32 + (tt >> 3)) * DKK + kk) * 8 + (tt & 7)] = pk4;
      } else {
        u16* op = arr == 0 ? wkF : wqF;
        size_t base = ((hb * 12 + (kk >> 3)) * NK) * 8 + (size_t)(kk & 7);
        #pragma unroll
        for (int e = 0; e < 4; ++e) {
          float val = acc[mi][ni][e] + bias;
          if (arr == 1) val *= QSCALE;
          op[base + (size_t)(tt + e) * 8] = f2bf(val);
        }
      }
    }
}

// ---------------------------------------------------------------------------
// Kernel 2: geometric bias via MFMA with two-term (hi+lo) bf16 split.
// Rows = flat (b,m,n) of pos [1048576 x 96]; W^T as B-operand (8 valid cols).
// x = pos.w computed as hi_p*hi_w + hi_p*lo_w + lo_p*hi_w  (lo*lo dropped,
// |err| ~ 4e-6 rel) -- restores fp32-grade accuracy that plain bf16 MFMA
// lost (R5 failure: log() amplifies 1e-3 dot error near relu boundary).
// ---------------------------------------------------------------------------
__global__ __launch_bounds__(256) void wg_kernel(
    const float* __restrict__ pos,
    const float* __restrict__ WGw, const float* __restrict__ WGb,
    u16* __restrict__ lb2)
{
  __shared__ u16 Th[128 * 104];          // hi plane, rows padded 96->104
  __shared__ u16 Tl[128 * 104];          // lo plane
  const int t = threadIdx.x;
  const int lane = t & 63, w = t >> 6;
  const int c = lane & 15, g = lane >> 4;
  const size_t row0 = (size_t)blockIdx.x * 128;

  // B-frags (hi/lo): lane (c,g) holds W[c&7][kc*32+g*8 .. +8]
  s16x8 bwh[3], bwl[3];
  #pragma unroll
  for (int kc = 0; kc < 3; ++kc) {
    const float* wp = WGw + (c & 7) * DKK + kc * 32 + g * 8;
    s16x8 hv, lv;
    #pragma unroll
    for (int j = 0; j < 4; ++j) {
      float x0 = wp[2 * j], x1 = wp[2 * j + 1];
      u32 h = cvtpk(x0, x1);
      u32 l = cvtpk(x0 - bflo(h), x1 - bfhi(h));
      hv[2 * j] = (short)(h & 0xffff); hv[2 * j + 1] = (short)(h >> 16);
      lv[2 * j] = (short)(l & 0xffff); lv[2 * j + 1] = (short)(l >> 16);
    }
    bwh[kc] = hv; bwl[kc] = lv;
  }
  const float bias = WGb[c & 7];

  // stage: 1536 chunks of 8 floats; dense, fully coalesced f32x4 loads
  #pragma unroll
  for (int i = 0; i < 6; ++i) {
    int q = t + i * 256;
    int row = q / 12, col8 = q - row * 12;
    const float* s = pos + row0 * DKK + (size_t)q * 8;
    float4 a = *(const float4*)s;
    float4 b = *(const float4*)(s + 4);
    uint4 ph, pl;
    ph.x = cvtpk(a.x, a.y); pl.x = cvtpk(a.x - bflo(ph.x), a.y - bfhi(ph.x));
    ph.y = cvtpk(a.z, a.w); pl.y = cvtpk(a.z - bflo(ph.y), a.w - bfhi(ph.y));
    ph.z = cvtpk(b.x, b.y); pl.z = cvtpk(b.x - bflo(ph.z), b.y - bfhi(ph.z));
    ph.w = cvtpk(b.z, b.w); pl.w = cvtpk(b.z - bflo(ph.w), b.w - bfhi(ph.w));
    *(uint4*)&Th[row * 104 + col8 * 8] = ph;
    *(uint4*)&Tl[row * 104 + col8 * 8] = pl;
  }
  __syncthreads();

  // compute: wave w -> local rows w*32 .. w*32+31, two 16-row groups
  #pragma unroll
  for (int gi = 0; gi < 2; ++gi) {
    int rowl = w * 32 + gi * 16;
    f32x4 acc = {0.f, 0.f, 0.f, 0.f};
    #pragma unroll
    for (int kc = 0; kc < 3; ++kc) {
      s16x8 ah = *(const s16x8*)&Th[(rowl + c) * 104 + kc * 32 + g * 8];
      s16x8 al = *(const s16x8*)&Tl[(rowl + c) * 104 + kc * 32 + g * 8];
      acc = __builtin_amdgcn_mfma_f32_16x16x32_bf16(ah, bwh[kc], acc, 0, 0, 0);
      acc = __builtin_amdgcn_mfma_f32_16x16x32_bf16(ah, bwl[kc], acc, 0, 0, 0);
      acc = __builtin_amdgcn_mfma_f32_16x16x32_bf16(al, bwh[kc], acc, 0, 0, 0);
    }
    if (c < 8) {
      size_t base = (size_t)c * (NB * NK * NK) + row0 + rowl + g * 4;
      #pragma unroll
      for (int e = 0; e < 4; ++e) {
        float v = __logf(fmaxf(acc[e] + bias, 1e-6f));
        lb2[base + e] = f2bf(v);
      }
    }
  }
}

// ---------------------------------------------------------------------------
// Kernel 3: attention.  512 blocks (4 nb x 16 b x 8 r), 4 waves each, wave owns
// 16 query rows (n).  All K/Q/V frag loads are dense 1-KB instrs (frag-major
// layouts); bias preloaded; softmax in-reg; PV via tiny per-wave LDS P chunks.
// ---------------------------------------------------------------------------
__global__ __launch_bounds__(256) void attn_kernel(
    const u16* __restrict__ wkF, const u16* __restrict__ wqF,
    const u16* __restrict__ wvF, const u16* __restrict__ lb2,
    const float* __restrict__ fa, float* __restrict__ out)
{
  __shared__ u16 Ps[4][16][40];   // per-wave P chunk [16 n][32 m]
  const int t = threadIdx.x;
  const int w = t >> 6, lane = t & 63;
  const int c = lane & 15, g = lane >> 4;
  const int b = blockIdx.y, r = blockIdx.z;
  const int nb = blockIdx.x * 64 + w * 16;

  const size_t hb = (size_t)r * NB + b;
  const u16* Qb = wqF + hb * (12 * NK * 8);
  const u16* Kb = wkF + hb * (12 * NK * 8);
  const u16* Vb = wvF + hb * (32 * DKK * 8);
  const u16* Br = lb2 + hb * NK * NK + (size_t)c * NK + nb + g * 4;

  s16x8 qf[3];
  #pragma unroll
  for (int kc = 0; kc < 3; ++kc)
    qf[kc] = *(const s16x8*)(Qb + ((kc * 4 + g) * NK + nb + c) * 8);

  // preload all 16 bias quads
  ushort4 bbr[16];
  #pragma unroll
  for (int mt = 0; mt < 16; ++mt)
    bbr[mt] = *(const ushort4*)(Br + (size_t)mt * 16 * NK);

  // S[n = nb+g*4+e][m = mt*16+c]
  f32x4 S[16];
  #pragma unroll
  for (int mt = 0; mt < 16; ++mt) {
    f32x4 sa = {bf2f(bbr[mt].x), bf2f(bbr[mt].y), bf2f(bbr[mt].z), bf2f(bbr[mt].w)};
    #pragma unroll
    for (int kc = 0; kc < 3; ++kc) {
      s16x8 kf = *(const s16x8*)(Kb + ((kc * 4 + g) * NK + mt * 16 + c) * 8);
      sa = __builtin_amdgcn_mfma_f32_16x16x32_bf16(qf[kc], kf, sa, 0, 0, 0);
    }
    S[mt] = sa;
  }

  // softmax over m: 16 in-lane + shfl_xor over the 16 c-lanes
  float rinv[4];
  #pragma unroll
  for (int e = 0; e < 4; ++e) {
    float mx = S[0][e];
    #pragma unroll
    for (int mt = 1; mt < 16; ++mt) mx = fmaxf(mx, S[mt][e]);
    mx = fmaxf(mx, __shfl_xor(mx, 1));
    mx = fmaxf(mx, __shfl_xor(mx, 2));
    mx = fmaxf(mx, __shfl_xor(mx, 4));
    mx = fmaxf(mx, __shfl_xor(mx, 8));
    float sm = 0.f;
    #pragma unroll
    for (int mt = 0; mt < 16; ++mt) {
      float p = __expf(S[mt][e] - mx);
      S[mt][e] = p;
      sm += p;
    }
    sm += __shfl_xor(sm, 1);
    sm += __shfl_xor(sm, 2);
    sm += __shfl_xor(sm, 4);
    sm += __shfl_xor(sm, 8);
    rinv[e] = 1.f / sm;
  }

  // PV in 8 chunks of 32 m
  f32x4 o[6];
  #pragma unroll
  for (int ki = 0; ki < 6; ++ki) o[ki] = (f32x4){0.f, 0.f, 0.f, 0.f};

  #pragma unroll
  for (int mc = 0; mc < 8; ++mc) {
    #pragma unroll
    for (int e = 0; e < 4; ++e) {
      Ps[w][g * 4 + e][c]      = f2bf(S[2 * mc][e]);
      Ps[w][g * 4 + e][16 + c] = f2bf(S[2 * mc + 1][e]);
    }
    s16x8 pa = *(const s16x8*)&Ps[w][c][g * 8];
    #pragma unroll
    for (int ki = 0; ki < 6; ++ki) {
      s16x8 vf = *(const s16x8*)(Vb + ((mc * 4 + g) * DKK + ki * 16 + c) * 8);
      o[ki] = __builtin_amdgcn_mfma_f32_16x16x32_bf16(pa, vf, o[ki], 0, 0, 0);
    }
  }

  // epilogue: normalize, residual, fp32 store
  #pragma unroll
  for (int ki = 0; ki < 6; ++ki)
    #pragma unroll
    for (int e = 0; e < 4; ++e) {
      int n = nb + g * 4 + e;
      size_t adr = ((size_t)b * NK + n) * (NR * DKK) + r * DKK + ki * 16 + c;
      out[adr] = o[ki][e] * rinv[e] + fa[adr];
    }
}

extern "C" void kernel_launch(void* const* d_in, const int* in_sizes, int n_in,
                              void* d_out, int out_size, void* d_ws, size_t ws_size,
                              hipStream_t stream) {
  (void)in_sizes; (void)n_in; (void)out_size; (void)ws_size;
  const float* fa  = (const float*)d_in[0];
  const float* pos = (const float*)d_in[1];
  const float* WGw = (const float*)d_in[2];
  const float* WGb = (const float*)d_in[3];
  const float* WKw = (const float*)d_in[4];
  const float* WKb = (const float*)d_in[5];
  const float* WQw = (const float*)d_in[6];
  const float* WQb = (const float*)d_in[7];
  const float* WVw = (const float*)d_in[8];
  const float* WVb = (const float*)d_in[9];
  float* outp = (float*)d_out;

  const size_t faN = (size_t)NB * NK * APP;       // 3,145,728
  const size_t wN  = (size_t)3 * NR * DKK * APP;  // 1,769,472
  const size_t kqv = (size_t)NR * NB * NK * DKK;  // 3,145,728 (all 3 layouts)
  u16* fab = (u16*)d_ws;
  u16* Wb  = fab + faN;
  u16* wkF = Wb + wN;
  u16* wqF = wkF + kqv;
  u16* wvF = wqF + kqv;
  u16* lb2 = wvF + kqv;

  hipLaunchKernelGGL(conv_kernel, dim3(2400), dim3(256), 0, stream,
                     fa, WKw, WQw, WVw, fab, Wb);
  hipLaunchKernelGGL(proj_kernel, dim3(32, 18), dim3(256), 0, stream,
                     fab, Wb, WKb, WQb, WVb, wkF, wqF, wvF);
  hipLaunchKernelGGL(wg_kernel, dim3(8192), dim3(256), 0, stream,
                     pos, WGw, WGb, lb2);
  hipLaunchKernelGGL(attn_kernel, dim3(4, NB, NR), dim3(256), 0, stream,
                     wkF, wqF, wvF, lb2, fa, outp);
}

// Round 7
// 137.386 us; speedup vs baseline: 3.8375x; 1.0666x over previous
//
#include <hip/hip_runtime.h>
#include <hip/hip_bf16.h>

typedef __attribute__((ext_vector_type(8))) short s16x8;
typedef __attribute__((ext_vector_type(4))) float f32x4;
typedef unsigned short u16;
typedef unsigned int u32;

#define NB 16
#define NK 256
#define APP 768
#define DKK 96
#define NR 8
#define QSCALE 0.10206207261596575f   // 1/sqrt(96), folded into Q at projection

__device__ __forceinline__ u16 f2bf(float f) {
  union { float f; unsigned int u; } v; v.f = f;
  unsigned int x = v.u;
  x += 0x7fffu + ((x >> 16) & 1u);
  return (u16)(x >> 16);
}
__device__ __forceinline__ float bf2f(u16 h) {
  union { unsigned int u; float f; } v; v.u = ((unsigned int)h) << 16;
  return v.f;
}
__device__ __forceinline__ u32 cvtpk(float lo, float hi) {
  u32 r;
  asm("v_cvt_pk_bf16_f32 %0, %1, %2" : "=v"(r) : "v"(lo), "v"(hi));
  return r;
}
__device__ __forceinline__ float bflo(u32 pk) {   // float of low bf16
  union { u32 u; float f; } v; v.u = pk << 16; return v.f;
}
__device__ __forceinline__ float bfhi(u32 pk) {   // float of high bf16
  union { u32 u; float f; } v; v.u = pk & 0xffff0000u; return v.f;
}
__device__ __forceinline__ void gload_lds16(const void* g, void* l) {
  __builtin_amdgcn_global_load_lds(
      (const __attribute__((address_space(1))) unsigned int*)g,
      (__attribute__((address_space(3))) unsigned int*)l, 16, 0, 0);
}

// ---------------------------------------------------------------------------
// Kernel 0: convert f_a and the 3 projection weights to bf16.
// ---------------------------------------------------------------------------
__global__ __launch_bounds__(256) void conv_kernel(
    const float* __restrict__ fa,
    const float* __restrict__ WKw, const float* __restrict__ WQw,
    const float* __restrict__ WVw,
    u16* __restrict__ fab, u16* __restrict__ Wb)
{
  const int idx = blockIdx.x * 256 + threadIdx.x;
  const int faCh = NB * NK * APP / 8;      // 393216
  const int wCh  = NR * DKK * APP / 8;     // 73728 per weight array
  const float* src; u16* dst;
  if (idx < faCh) {
    src = fa + (size_t)idx * 8;
    dst = fab + (size_t)idx * 8;
  } else {
    int o = idx - faCh;
    int a = o / wCh;
    int oo = o - a * wCh;
    const float* wsrc = a == 0 ? WKw : (a == 1 ? WQw : WVw);
    src = wsrc + (size_t)oo * 8;
    dst = Wb + (size_t)a * (NR * DKK * APP) + (size_t)oo * 8;
  }
  float4 v0 = *(const float4*)src;
  float4 v1 = *(const float4*)(src + 4);
  s16x8 ov = {(short)f2bf(v0.x),(short)f2bf(v0.y),(short)f2bf(v0.z),(short)f2bf(v0.w),
              (short)f2bf(v1.x),(short)f2bf(v1.y),(short)f2bf(v1.z),(short)f2bf(v1.w)};
  *(s16x8*)dst = ov;
}

// ---------------------------------------------------------------------------
// Kernel 1 (FUSED proj + wg): one grid, proj block every 15th bid
// (576 proj : 8192 wg) so every CU co-hosts the MFMA-bound proj GEMM and the
// HBM-streaming wg pass -> proj hides under wg's bandwidth time.
// LDS aliased via one 53.2 KB array (proj uses 32 KB, wg all of it).
//
// proj: C[m,c]=fab[m,:].Wb[c,:]+bias, 128x128 tile, BK=64, gload_lds w=16,
//   both-sides XOR swizzle; frag-major outputs:
//     wkF/wqF: [r][b][kg=12][m=256][8]  (Q pre-scaled)
//     wvF    : [r][b][mg=32][kout=96][8]
// wg: lb2[r][flat(b,m,n)] = log(max(pos.WGw[r]+WGb[r],1e-6)) via 3-term
//   hi/lo bf16 MFMA split (fp32-grade accuracy); packed uint2 stores.
// ---------------------------------------------------------------------------
#define PROJ_BLKS 576
#define WG_BLKS 8192

__global__ __launch_bounds__(256) void fused_kernel(
    const u16* __restrict__ fab, const u16* __restrict__ Wb,
    const float* __restrict__ WKb, const float* __restrict__ WQb,
    const float* __restrict__ WVb,
    u16* __restrict__ wkF, u16* __restrict__ wqF, u16* __restrict__ wvF,
    const float* __restrict__ pos,
    const float* __restrict__ WGw, const float* __restrict__ WGb,
    u16* __restrict__ lb2)
{
  __shared__ u16 SH[26624];              // 53.2 KB, aliased by both paths
  const int t = threadIdx.x;
  const int lane = t & 63, w = t >> 6;
  const int c = lane & 15, g = lane >> 4;
  const int bid = blockIdx.x;
  const int q = bid / 15, rph = bid - q * 15;

  if (rph == 0 && q < PROJ_BLKS) {
    // ----------------------- proj path -----------------------
    u16* As = SH;                        // 8192 elems
    u16* Bs = SH + 8192;
    const int pb = q;
    const int wr = w >> 1, wc = w & 1;
    const int m0 = (pb & 31) * 128;
    const int ct = pb >> 5;              // 0..17
    const int c0 = ct * 128;

    f32x4 acc[4][4] = {};

    for (int k0 = 0; k0 < APP; k0 += 64) {
      __syncthreads();
      #pragma unroll
      for (int i = 0; i < 4; ++i) {
        int n = t + i * 256;             // chunk id, 0..1023
        int row = n >> 3, cg = n & 7;
        int scg = cg ^ (row & 7);        // pre-swizzled global col-group
        gload_lds16(fab + (size_t)(m0 + row) * APP + k0 + scg * 8, As + n * 8);
        gload_lds16(Wb  + (size_t)(c0 + row) * APP + k0 + scg * 8, Bs + n * 8);
      }
      __syncthreads();
      #pragma unroll
      for (int kc = 0; kc < 2; ++kc) {
        s16x8 af[4], bfr[4];
        #pragma unroll
        for (int i = 0; i < 4; ++i) {
          int arow = wr * 64 + i * 16 + c;
          af[i]  = *(const s16x8*)(As + (((arow << 3) | ((kc * 4 + g) ^ (arow & 7))) << 3));
          int brow = wc * 64 + i * 16 + c;
          bfr[i] = *(const s16x8*)(Bs + (((brow << 3) | ((kc * 4 + g) ^ (brow & 7))) << 3));
        }
        #pragma unroll
        for (int mi = 0; mi < 4; ++mi)
          #pragma unroll
          for (int ni = 0; ni < 4; ++ni)
            acc[mi][ni] = __builtin_amdgcn_mfma_f32_16x16x32_bf16(af[mi], bfr[ni], acc[mi][ni], 0, 0, 0);
      }
    }

    const int arr = ct / 6;              // 0=K 1=Q 2=V (tiles never straddle)
    const int cw0 = c0 - arr * APP;
    const float* bp = arr == 0 ? WKb : (arr == 1 ? WQb : WVb);

    #pragma unroll
    for (int mi = 0; mi < 4; ++mi)
      #pragma unroll
      for (int ni = 0; ni < 4; ++ni) {
        int clw = cw0 + wc * 64 + ni * 16 + c;    // 0..767
        float bias = bp[clw];
        int rr = clw / DKK, kk = clw - rr * DKK;  // r, k-within-head
        int mb = m0 + wr * 64 + mi * 16 + g * 4;  // 4 consecutive m
        int bi = mb >> 8, tt = mb & 255;
        size_t hb = (size_t)rr * NB + bi;
        if (arr == 2) {
          ushort4 pk4;
          pk4.x = f2bf(acc[mi][ni][0] + bias);
          pk4.y = f2bf(acc[mi][ni][1] + bias);
          pk4.z = f2bf(acc[mi][ni][2] + bias);
          pk4.w = f2bf(acc[mi][ni][3] + bias);
          *(ushort4*)&wvF[((hb * 32 + (tt >> 3)) * DKK + kk) * 8 + (tt & 7)] = pk4;
        } else {
          u16* op = arr == 0 ? wkF : wqF;
          size_t base = ((hb * 12 + (kk >> 3)) * NK) * 8 + (size_t)(kk & 7);
          #pragma unroll
          for (int e = 0; e < 4; ++e) {
            float val = acc[mi][ni][e] + bias;
            if (arr == 1) val *= QSCALE;
            op[base + (size_t)(tt + e) * 8] = f2bf(val);
          }
        }
      }
  } else {
    // ----------------------- wg path -----------------------
    const int nbefore = (q >= PROJ_BLKS) ? PROJ_BLKS : (q + (rph > 0 ? 1 : 0));
    const int wgid = bid - nbefore;      // 0..8191
    u16* Th = SH;                        // hi plane, 13312 elems (rows 96->104)
    u16* Tl = SH + 13312;                // lo plane
    const size_t row0 = (size_t)wgid * 128;

    // B-frags (hi/lo): lane (c,g) holds W[c&7][kc*32+g*8 .. +8]
    s16x8 bwh[3], bwl[3];
    #pragma unroll
    for (int kc = 0; kc < 3; ++kc) {
      const float* wp = WGw + (c & 7) * DKK + kc * 32 + g * 8;
      s16x8 hv, lv;
      #pragma unroll
      for (int j = 0; j < 4; ++j) {
        float x0 = wp[2 * j], x1 = wp[2 * j + 1];
        u32 h = cvtpk(x0, x1);
        u32 l = cvtpk(x0 - bflo(h), x1 - bfhi(h));
        hv[2 * j] = (short)(h & 0xffff); hv[2 * j + 1] = (short)(h >> 16);
        lv[2 * j] = (short)(l & 0xffff); lv[2 * j + 1] = (short)(l >> 16);
      }
      bwh[kc] = hv; bwl[kc] = lv;
    }
    const float bias = WGb[c & 7];

    // stage: 1536 chunks of 8 floats; dense, fully coalesced f32x4 loads
    #pragma unroll
    for (int i = 0; i < 6; ++i) {
      int qq = t + i * 256;
      int row = qq / 12, col8 = qq - row * 12;
      const float* s = pos + row0 * DKK + (size_t)qq * 8;
      float4 a = *(const float4*)s;
      float4 b = *(const float4*)(s + 4);
      uint4 ph, pl;
      ph.x = cvtpk(a.x, a.y); pl.x = cvtpk(a.x - bflo(ph.x), a.y - bfhi(ph.x));
      ph.y = cvtpk(a.z, a.w); pl.y = cvtpk(a.z - bflo(ph.y), a.w - bfhi(ph.y));
      ph.z = cvtpk(b.x, b.y); pl.z = cvtpk(b.x - bflo(ph.z), b.y - bfhi(ph.z));
      ph.w = cvtpk(b.z, b.w); pl.w = cvtpk(b.z - bflo(ph.w), b.w - bfhi(ph.w));
      *(uint4*)&Th[row * 104 + col8 * 8] = ph;
      *(uint4*)&Tl[row * 104 + col8 * 8] = pl;
    }
    __syncthreads();

    // compute: wave w -> local rows w*32 .. w*32+31, two 16-row groups
    #pragma unroll
    for (int gi = 0; gi < 2; ++gi) {
      int rowl = w * 32 + gi * 16;
      f32x4 acc = {0.f, 0.f, 0.f, 0.f};
      #pragma unroll
      for (int kc = 0; kc < 3; ++kc) {
        s16x8 ah = *(const s16x8*)&Th[(rowl + c) * 104 + kc * 32 + g * 8];
        s16x8 al = *(const s16x8*)&Tl[(rowl + c) * 104 + kc * 32 + g * 8];
        acc = __builtin_amdgcn_mfma_f32_16x16x32_bf16(ah, bwh[kc], acc, 0, 0, 0);
        acc = __builtin_amdgcn_mfma_f32_16x16x32_bf16(ah, bwl[kc], acc, 0, 0, 0);
        acc = __builtin_amdgcn_mfma_f32_16x16x32_bf16(al, bwh[kc], acc, 0, 0, 0);
      }
      if (c < 8) {
        size_t base = (size_t)c * (NB * NK * NK) + row0 + rowl + g * 4;
        float v0 = __logf(fmaxf(acc[0] + bias, 1e-6f));
        float v1 = __logf(fmaxf(acc[1] + bias, 1e-6f));
        float v2 = __logf(fmaxf(acc[2] + bias, 1e-6f));
        float v3 = __logf(fmaxf(acc[3] + bias, 1e-6f));
        uint2 pk;
        pk.x = cvtpk(v0, v1);
        pk.y = cvtpk(v2, v3);
        *(uint2*)(lb2 + base) = pk;      // 8B packed store
      }
    }
  }
}

// ---------------------------------------------------------------------------
// Kernel 2: attention.  512 blocks (4 nb x 16 b x 8 r), 4 waves each, wave owns
// 16 query rows (n).  All K/Q/V frag loads are dense 1-KB instrs (frag-major
// layouts); bias preloaded; softmax in-reg; PV via tiny per-wave LDS P chunks.
// ---------------------------------------------------------------------------
__global__ __launch_bounds__(256) void attn_kernel(
    const u16* __restrict__ wkF, const u16* __restrict__ wqF,
    const u16* __restrict__ wvF, const u16* __restrict__ lb2,
    const float* __restrict__ fa, float* __restrict__ out)
{
  __shared__ u16 Ps[4][16][40];   // per-wave P chunk [16 n][32 m]
  const int t = threadIdx.x;
  const int w = t >> 6, lane = t & 63;
  const int c = lane & 15, g = lane >> 4;
  const int b = blockIdx.y, r = blockIdx.z;
  const int nb = blockIdx.x * 64 + w * 16;

  const size_t hb = (size_t)r * NB + b;
  const u16* Qb = wqF + hb * (12 * NK * 8);
  const u16* Kb = wkF + hb * (12 * NK * 8);
  const u16* Vb = wvF + hb * (32 * DKK * 8);
  const u16* Br = lb2 + hb * NK * NK + (size_t)c * NK + nb + g * 4;

  s16x8 qf[3];
  #pragma unroll
  for (int kc = 0; kc < 3; ++kc)
    qf[kc] = *(const s16x8*)(Qb + ((kc * 4 + g) * NK + nb + c) * 8);

  // preload all 16 bias quads
  ushort4 bbr[16];
  #pragma unroll
  for (int mt = 0; mt < 16; ++mt)
    bbr[mt] = *(const ushort4*)(Br + (size_t)mt * 16 * NK);

  // S[n = nb+g*4+e][m = mt*16+c]
  f32x4 S[16];
  #pragma unroll
  for (int mt = 0; mt < 16; ++mt) {
    f32x4 sa = {bf2f(bbr[mt].x), bf2f(bbr[mt].y), bf2f(bbr[mt].z), bf2f(bbr[mt].w)};
    #pragma unroll
    for (int kc = 0; kc < 3; ++kc) {
      s16x8 kf = *(const s16x8*)(Kb + ((kc * 4 + g) * NK + mt * 16 + c) * 8);
      sa = __builtin_amdgcn_mfma_f32_16x16x32_bf16(qf[kc], kf, sa, 0, 0, 0);
    }
    S[mt] = sa;
  }

  // softmax over m: 16 in-lane + shfl_xor over the 16 c-lanes
  float rinv[4];
  #pragma unroll
  for (int e = 0; e < 4; ++e) {
    float mx = S[0][e];
    #pragma unroll
    for (int mt = 1; mt < 16; ++mt) mx = fmaxf(mx, S[mt][e]);
    mx = fmaxf(mx, __shfl_xor(mx, 1));
    mx = fmaxf(mx, __shfl_xor(mx, 2));
    mx = fmaxf(mx, __shfl_xor(mx, 4));
    mx = fmaxf(mx, __shfl_xor(mx, 8));
    float sm = 0.f;
    #pragma unroll
    for (int mt = 0; mt < 16; ++mt) {
      float p = __expf(S[mt][e] - mx);
      S[mt][e] = p;
      sm += p;
    }
    sm += __shfl_xor(sm, 1);
    sm += __shfl_xor(sm, 2);
    sm += __shfl_xor(sm, 4);
    sm += __shfl_xor(sm, 8);
    rinv[e] = 1.f / sm;
  }

  // PV in 8 chunks of 32 m
  f32x4 o[6];
  #pragma unroll
  for (int ki = 0; ki < 6; ++ki) o[ki] = (f32x4){0.f, 0.f, 0.f, 0.f};

  #pragma unroll
  for (int mc = 0; mc < 8; ++mc) {
    #pragma unroll
    for (int e = 0; e < 4; ++e) {
      Ps[w][g * 4 + e][c]      = f2bf(S[2 * mc][e]);
      Ps[w][g * 4 + e][16 + c] = f2bf(S[2 * mc + 1][e]);
    }
    s16x8 pa = *(const s16x8*)&Ps[w][c][g * 8];
    #pragma unroll
    for (int ki = 0; ki < 6; ++ki) {
      s16x8 vf = *(const s16x8*)(Vb + ((mc * 4 + g) * DKK + ki * 16 + c) * 8);
      o[ki] = __builtin_amdgcn_mfma_f32_16x16x32_bf16(pa, vf, o[ki], 0, 0, 0);
    }
  }

  // epilogue: normalize, residual, fp32 store
  #pragma unroll
  for (int ki = 0; ki < 6; ++ki)
    #pragma unroll
    for (int e = 0; e < 4; ++e) {
      int n = nb + g * 4 + e;
      size_t adr = ((size_t)b * NK + n) * (NR * DKK) + r * DKK + ki * 16 + c;
      out[adr] = o[ki][e] * rinv[e] + fa[adr];
    }
}

extern "C" void kernel_launch(void* const* d_in, const int* in_sizes, int n_in,
                              void* d_out, int out_size, void* d_ws, size_t ws_size,
                              hipStream_t stream) {
  (void)in_sizes; (void)n_in; (void)out_size; (void)ws_size;
  const float* fa  = (const float*)d_in[0];
  const float* pos = (const float*)d_in[1];
  const float* WGw = (const float*)d_in[2];
  const float* WGb = (const float*)d_in[3];
  const float* WKw = (const float*)d_in[4];
  const float* WKb = (const float*)d_in[5];
  const float* WQw = (const float*)d_in[6];
  const float* WQb = (const float*)d_in[7];
  const float* WVw = (const float*)d_in[8];
  const float* WVb = (const float*)d_in[9];
  float* outp = (float*)d_out;

  const size_t faN = (size_t)NB * NK * APP;       // 3,145,728
  const size_t wN  = (size_t)3 * NR * DKK * APP;  // 1,769,472
  const size_t kqv = (size_t)NR * NB * NK * DKK;  // 3,145,728 (all 3 layouts)
  u16* fab = (u16*)d_ws;
  u16* Wb  = fab + faN;
  u16* wkF = Wb + wN;
  u16* wqF = wkF + kqv;
  u16* wvF = wqF + kqv;
  u16* lb2 = wvF + kqv;

  hipLaunchKernelGGL(conv_kernel, dim3(2400), dim3(256), 0, stream,
                     fa, WKw, WQw, WVw, fab, Wb);
  hipLaunchKernelGGL(fused_kernel, dim3(PROJ_BLKS + WG_BLKS), dim3(256), 0, stream,
                     fab, Wb, WKb, WQb, WVb, wkF, wqF, wvF, pos, WGw, WGb, lb2);
  hipLaunchKernelGGL(attn_kernel, dim3(4, NB, NR), dim3(256), 0, stream,
                     wkF, wqF, wvF, lb2, fa, outp);
}